// Round 7
// baseline (640.927 us; speedup 1.0000x reference)
//
#include <hip/hip_runtime.h>
#include <hip/hip_bf16.h>
#include <math.h>

#define NROW   8192      // B*H*W z-rows
#define KCODE  8192      // codebook entries
#define CD     256
#define HWSZ   1024
#define NBLK   32        // 256-code blocks for top-3 candidates
#define MARGIN 7.5e-5f

#define QOFF   ((size_t)NROW * CD)   // 2097152: loss at QOFF, indices at QOFF+1

typedef __attribute__((ext_vector_type(8))) short short8;
typedef __attribute__((ext_vector_type(4))) float f32x4;
typedef unsigned long long u64;

// sortable key: high32 = monotone float map, low32 = code (lex tie -> low index)
__device__ __forceinline__ u64 makeKey(float v, int code) {
  unsigned u = __float_as_uint(v);
  unsigned m = (u & 0x80000000u) ? ~u : (u | 0x80000000u);
  return ((u64)m << 32) | (unsigned)code;
}
__device__ __forceinline__ float keyVal(u64 k) {
  unsigned m = (unsigned)(k >> 32);
  unsigned u = (m & 0x80000000u) ? (m ^ 0x80000000u) : ~m;
  return __uint_as_float(u);
}
__device__ __forceinline__ void ins3(u64 k, u64& t1, u64& t2, u64& t3) {
  if (k < t1) { t3 = t2; t2 = t1; t1 = k; }
  else if (k < t2) { t3 = t2; t2 = k; }
  else if (k < t3) { t3 = k; }
}

// ---------------- k1: z -> Xhi bf16 [n][c] + exact-numpy x2 (R2-proven) ----------------
__global__ __launch_bounds__(256) void splitz_x2_kernel(
    const float* __restrict__ z, unsigned short* __restrict__ Xhi,
    float* __restrict__ x2g) {
  __shared__ float xs[32 * 260];
  int tid = threadIdx.x;
  int n0 = blockIdx.x * 32;
  int b = n0 >> 10;
  int hw0 = n0 & 1023;
  const float* zb = z + (size_t)b * (CD * HWSZ) + hw0;
  {
    int r = tid & 31;
    int cbase = tid >> 5;
    for (int it = 0; it < 32; ++it) {
      int c = cbase + it * 8;
      xs[r * 260 + c] = zb[(size_t)c * HWSZ + r];
    }
  }
  __syncthreads();
  if (tid < 32) {
#pragma clang fp contract(off)
    const float* xr = &xs[tid * 260];
    float r0[8], r1[8];
#pragma unroll
    for (int j = 0; j < 8; ++j) {
      float v = xr[j];       r0[j] = v * v;
      float w = xr[128 + j]; r1[j] = w * w;
    }
    for (int i = 8; i < 128; i += 8) {
#pragma unroll
      for (int j = 0; j < 8; ++j) {
        float v = xr[i + j];       float a  = v * v; r0[j] = r0[j] + a;
        float w = xr[128 + i + j]; float b2 = w * w; r1[j] = r1[j] + b2;
      }
    }
    float lo = ((r0[0] + r0[1]) + (r0[2] + r0[3])) + ((r0[4] + r0[5]) + (r0[6] + r0[7]));
    float hi = ((r1[0] + r1[1]) + (r1[2] + r1[3])) + ((r1[4] + r1[5]) + (r1[6] + r1[7]));
    x2g[n0 + tid] = lo + hi;
  }
  for (int r = 0; r < 32; ++r) {
    float v = xs[r * 260 + tid];
    __hip_bfloat16 h = __float2bfloat16(v);
    Xhi[(size_t)(n0 + r) * CD + tid] = *(unsigned short*)&h;
  }
}

// ---------------- k2: emb -> Ehi bf16 [k][c] ----------------
__global__ __launch_bounds__(256) void splite_kernel(
    const float* __restrict__ emb, unsigned short* __restrict__ Ehi) {
  int n = blockIdx.x * 256 + threadIdx.x;
  __hip_bfloat16 h = __float2bfloat16(emb[n]);
  Ehi[n] = *(unsigned short*)&h;
}

// ---------------- k3: barrier-free LDS-free MFMA GEMM + per-256-code top-3 ----------------
// Each wave owns 64 codes x 128 zrows; frags loaded DIRECTLY from global
// (16x64B full cache lines per load instr, operands L2-resident). 2-deep
// register pipeline, zero main-loop barriers. One barrier for 4-wave combine.
__global__ __launch_bounds__(256, 2) void gemm_top3_kernel(
    const unsigned short* __restrict__ Eg,   // A [8192][256] bf16
    const unsigned short* __restrict__ Xg,   // B [8192][256] bf16
    u64* __restrict__ pK1, u64* __restrict__ pK2, u64* __restrict__ pK3) {
  __shared__ u64 redK[4][128][3];   // 12 KB

  int tid = threadIdx.x;
  int bid = blockIdx.x;             // 0..2047
  // XCD-chunked mapping: xcd = bid%8 owns cbx strip [xcd*4, xcd*4+4), rby 0..63,
  // traversed in 4x8 sub-chunks (working set ~1MB per L2).
  int xcd = bid & 7;
  int t   = bid >> 3;               // 0..255
  int rby_c = t >> 5;               // 0..7
  int r     = t & 31;
  int cbx = xcd * 4 + (r & 3);      // 0..31
  int rby = rby_c * 8 + (r >> 2);   // 0..63
  int wid = tid >> 6, lane = tid & 63;
  int llo = lane & 15, lhi = lane >> 4;
  int cb0w = cbx * 256 + wid * 64;  // this wave's 64 codes
  int rb0  = rby * 128;             // this wave's 128 zrows

  f32x4 acc[4][8];
#pragma unroll
  for (int i = 0; i < 4; ++i)
#pragma unroll
    for (int j = 0; j < 8; ++j) acc[i][j] = (f32x4){0.f, 0.f, 0.f, 0.f};

  // frag base addresses: row = base + 16*frag + llo, 16B k-slice at lhi*16
  const char* Ab = (const char*)Eg + ((size_t)(cb0w + llo)) * 512 + lhi * 16;
  const char* Bb = (const char*)Xg + ((size_t)(rb0  + llo)) * 512 + lhi * 16;

#define LA(dst, ks) { _Pragma("unroll") for (int i = 0; i < 4; ++i) \
    dst[i] = *(const short8*)(Ab + (size_t)i * 8192 + (ks) * 64); }
#define LB(dst, ks) { _Pragma("unroll") for (int j = 0; j < 8; ++j) \
    dst[j] = *(const short8*)(Bb + (size_t)j * 8192 + (ks) * 64); }
#define STEP(a, b) { _Pragma("unroll") for (int i = 0; i < 4; ++i) \
    _Pragma("unroll") for (int j = 0; j < 8; ++j) \
      acc[i][j] = __builtin_amdgcn_mfma_f32_16x16x32_bf16(a[i], b[j], acc[i][j], 0, 0, 0); }

  short8 a0[4], b0[8], a1[4], b1[8];
  LA(a0, 0) LB(b0, 0)
  LA(a1, 1) LB(b1, 1)
#pragma unroll
  for (int ks = 0; ks < 8; ks += 2) {
    STEP(a0, b0)
    if (ks + 2 < 8) { LA(a0, ks + 2) LB(b0, ks + 2) }
    STEP(a1, b1)
    if (ks + 3 < 8) { LA(a1, ks + 3) LB(b1, ks + 3) }
  }
#undef LA
#undef LB
#undef STEP

  // epilogue: v = -2*dot (x2 cancels per-row; monotone), top-3 per 64 codes,
  // reduce over lhi groups (xor 16,32 preserves llo). C/D layout m89-verified:
  // zrow = rb0 + 16j + llo, code = cb0w + 16i + 4*lhi + r4.  (R5-validated)
#pragma unroll
  for (int j = 0; j < 8; ++j) {
    u64 t1 = ~0ull, t2 = ~0ull, t3 = ~0ull;
#pragma unroll
    for (int i = 0; i < 4; ++i)
#pragma unroll
      for (int r4 = 0; r4 < 4; ++r4) {
        float v = -2.0f * acc[i][j][r4];
        int code = cb0w + 16 * i + 4 * lhi + r4;
        ins3(makeKey(v, code), t1, t2, t3);
      }
#pragma unroll
    for (int off = 16; off < 64; off <<= 1) {
      u64 o1 = __shfl_xor(t1, off, 64);
      u64 o2 = __shfl_xor(t2, off, 64);
      u64 o3 = __shfl_xor(t3, off, 64);
      ins3(o1, t1, t2, t3); ins3(o2, t1, t2, t3); ins3(o3, t1, t2, t3);
    }
    if (lhi == 0) {
      int zl = 16 * j + llo;
      redK[wid][zl][0] = t1; redK[wid][zl][1] = t2; redK[wid][zl][2] = t3;
    }
  }
  __syncthreads();
  if (tid < 128) {
    u64 t1 = redK[0][tid][0], t2 = redK[0][tid][1], t3 = redK[0][tid][2];
#pragma unroll
    for (int w = 1; w < 4; ++w) {
      ins3(redK[w][tid][0], t1, t2, t3);
      ins3(redK[w][tid][1], t1, t2, t3);
      ins3(redK[w][tid][2], t1, t2, t3);
    }
    size_t o = (size_t)cbx * NROW + rb0 + tid;
    pK1[o] = t1; pK2[o] = t2; pK3[o] = t3;
  }
}

// ---------------- k4: merge blocks + exact re-rank (R2 semantics, R5-validated) ----------------
__global__ __launch_bounds__(256) void merge_rerank_kernel(
    const float* __restrict__ z, const float* __restrict__ emb,
    const u64* __restrict__ pK1, const u64* __restrict__ pK2,
    const u64* __restrict__ pK3, const float* __restrict__ x2g,
    int* __restrict__ idx, float* __restrict__ out) {
  int n = blockIdx.x * 256 + threadIdx.x;
  u64 kmin = ~0ull;
  for (int blk = 0; blk < NBLK; ++blk) {
    u64 k = pK1[(size_t)blk * NROW + n];
    if (k < kmin) kmin = k;
  }
  float vcut = keyVal(kmin) + MARGIN;
  int cand[8]; int nc = 0;
  for (int blk = 0; blk < NBLK; ++blk) {
    size_t o = (size_t)blk * NROW + n;
    u64 k1 = pK1[o], k2 = pK2[o], k3 = pK3[o];
    if (keyVal(k1) <= vcut && nc < 8) cand[nc++] = (int)(k1 & 0xffffffffu);
    if (keyVal(k2) <= vcut && nc < 8) cand[nc++] = (int)(k2 & 0xffffffffu);
    if (keyVal(k3) <= vcut && nc < 8) cand[nc++] = (int)(k3 & 0xffffffffu);
  }
  int b = n >> 10, hw = n & 1023;
  const float* zp = z + (size_t)b * (CD * HWSZ) + hw;
  float x2 = x2g[n];
  float bs = INFINITY; int bi = 0x7fffffff;
  for (int c0 = 0; c0 < nc; ++c0) {
    int k = cand[c0];
    const float* ep = emb + (size_t)k * CD;
    float acc = 0.f;
    for (int c = 0; c < CD; ++c)                 // sequential fmaf chain == R2 dot
      acc = fmaf(zp[(size_t)c * HWSZ], ep[c], acc);
    float s = fmaf(-2.f, acc, x2);               // single rounding == np grid
    if (s < bs || (s == bs && k < bi)) { bs = s; bi = k; }
  }
  idx[n] = bi;
  out[QOFF + 1 + n] = (float)bi;
}

// ---------------- k5: gather quantized + loss partials (R2-proven) ----------------
__global__ __launch_bounds__(256) void gather_kernel(
    const float* __restrict__ z, const float* __restrict__ emb,
    const int* __restrict__ idx, float* __restrict__ out,
    float* __restrict__ lossPart) {
  __shared__ int sidx[64];
  __shared__ float swsum[4];
  int tid = threadIdx.x;
  int bid = blockIdx.x;
  int n0 = bid * 64;
  if (tid < 64) sidx[tid] = idx[n0 + tid];
  __syncthreads();
  int lane = tid & 63;
  int cw = tid >> 6;
  int b = n0 >> 10;
  int hw = (n0 & 1023) + lane;
  const float* erow = emb + (size_t)sidx[lane] * CD;
  float lacc = 0.f;
  for (int ci = 0; ci < 64; ++ci) {
    int c = cw * 64 + ci;
    float q = erow[c];
    size_t o = (size_t)b * (CD * HWSZ) + (size_t)c * HWSZ + hw;
    float zv = z[o];
    out[o] = q;
    float d = q - zv;
    lacc += d * d;
  }
#pragma unroll
  for (int off = 32; off > 0; off >>= 1) lacc += __shfl_down(lacc, off, 64);
  if (lane == 0) swsum[cw] = lacc;
  __syncthreads();
  if (tid == 0) lossPart[bid] = swsum[0] + swsum[1] + swsum[2] + swsum[3];
}

__global__ void loss_kernel(const float* __restrict__ lossPart, float* __restrict__ out) {
  if (threadIdx.x == 0) {
    double s = 0.0;
    for (int i = 0; i < 128; ++i) s += (double)lossPart[i];
    out[QOFF] = (float)(s * 1.25 / (double)(NROW * CD));
  }
}

extern "C" void kernel_launch(void* const* d_in, const int* in_sizes, int n_in,
                              void* d_out, int out_size, void* d_ws, size_t ws_size,
                              hipStream_t stream) {
  const float* z   = (const float*)d_in[0];
  const float* emb = (const float*)d_in[1];
  float* out = (float*)d_out;

  // bf16 operands live in d_out's 8MB quantized region (overwritten by gather later)
  unsigned short* Ehi = (unsigned short*)d_out;                       // 4 MB
  unsigned short* Xhi = (unsigned short*)d_out + (size_t)KCODE * CD;  // 4 MB

  // ws: pK1|pK2|pK3 (3 x 2 MB) | x2 | idx | lossPart  -> ~6.07 MB total
  u64* pK1 = (u64*)d_ws;
  u64* pK2 = pK1 + (size_t)NBLK * NROW;
  u64* pK3 = pK2 + (size_t)NBLK * NROW;
  float* x2g = (float*)(pK3 + (size_t)NBLK * NROW);
  int* idx = (int*)(x2g + NROW);
  float* lossPart = (float*)(idx + NROW);

  hipLaunchKernelGGL(splitz_x2_kernel, dim3(NROW / 32), dim3(256), 0, stream, z, Xhi, x2g);
  hipLaunchKernelGGL(splite_kernel, dim3((KCODE * CD) / 256), dim3(256), 0, stream, emb, Ehi);
  hipLaunchKernelGGL(gemm_top3_kernel, dim3((KCODE / 256) * (NROW / 128)), dim3(256), 0, stream,
                     Ehi, Xhi, pK1, pK2, pK3);
  hipLaunchKernelGGL(merge_rerank_kernel, dim3(NROW / 256), dim3(256), 0, stream,
                     z, emb, pK1, pK2, pK3, x2g, idx, out);
  hipLaunchKernelGGL(gather_kernel, dim3(NROW / 64), dim3(256), 0, stream,
                     z, emb, idx, out, lossPart);
  hipLaunchKernelGGL(loss_kernel, dim3(1), dim3(64), 0, stream, lossPart, out);
}

// Round 8
// 637.523 us; speedup vs baseline: 1.0053x; 1.0053x over previous
//
#include <hip/hip_runtime.h>
#include <hip/hip_bf16.h>
#include <math.h>

#define NROW   8192      // B*H*W z-rows
#define KCODE  8192      // codebook entries
#define CD     256
#define HWSZ   1024
#define NBLK   32        // 256-code blocks for top-3 candidates
#define MARGIN 7.5e-5f

#define QOFF   ((size_t)NROW * CD)   // 2097152: loss at QOFF, indices at QOFF+1

typedef __attribute__((ext_vector_type(8))) short short8;
typedef __attribute__((ext_vector_type(4))) float f32x4;
typedef unsigned long long u64;

// sortable key: high32 = monotone float map, low32 = code (lex tie -> low index)
__device__ __forceinline__ u64 makeKey(float v, int code) {
  unsigned u = __float_as_uint(v);
  unsigned m = (u & 0x80000000u) ? ~u : (u | 0x80000000u);
  return ((u64)m << 32) | (unsigned)code;
}
__device__ __forceinline__ float keyVal(u64 k) {
  unsigned m = (unsigned)(k >> 32);
  unsigned u = (m & 0x80000000u) ? (m ^ 0x80000000u) : ~m;
  return __uint_as_float(u);
}
__device__ __forceinline__ void ins3(u64 k, u64& t1, u64& t2, u64& t3) {
  if (k < t1) { t3 = t2; t2 = t1; t1 = k; }
  else if (k < t2) { t3 = t2; t2 = k; }
  else if (k < t3) { t3 = k; }
}

// ---------------- k1: z -> Xhi bf16 [n][c] + exact-numpy x2 (R2-proven) ----------------
__global__ __launch_bounds__(256) void splitz_x2_kernel(
    const float* __restrict__ z, unsigned short* __restrict__ Xhi,
    float* __restrict__ x2g) {
  __shared__ float xs[32 * 260];
  int tid = threadIdx.x;
  int n0 = blockIdx.x * 32;
  int b = n0 >> 10;
  int hw0 = n0 & 1023;
  const float* zb = z + (size_t)b * (CD * HWSZ) + hw0;
  {
    int r = tid & 31;
    int cbase = tid >> 5;
    for (int it = 0; it < 32; ++it) {
      int c = cbase + it * 8;
      xs[r * 260 + c] = zb[(size_t)c * HWSZ + r];
    }
  }
  __syncthreads();
  if (tid < 32) {
#pragma clang fp contract(off)
    const float* xr = &xs[tid * 260];
    float r0[8], r1[8];
#pragma unroll
    for (int j = 0; j < 8; ++j) {
      float v = xr[j];       r0[j] = v * v;
      float w = xr[128 + j]; r1[j] = w * w;
    }
    for (int i = 8; i < 128; i += 8) {
#pragma unroll
      for (int j = 0; j < 8; ++j) {
        float v = xr[i + j];       float a  = v * v; r0[j] = r0[j] + a;
        float w = xr[128 + i + j]; float b2 = w * w; r1[j] = r1[j] + b2;
      }
    }
    float lo = ((r0[0] + r0[1]) + (r0[2] + r0[3])) + ((r0[4] + r0[5]) + (r0[6] + r0[7]));
    float hi = ((r1[0] + r1[1]) + (r1[2] + r1[3])) + ((r1[4] + r1[5]) + (r1[6] + r1[7]));
    x2g[n0 + tid] = lo + hi;
  }
  for (int r = 0; r < 32; ++r) {
    float v = xs[r * 260 + tid];
    __hip_bfloat16 h = __float2bfloat16(v);
    Xhi[(size_t)(n0 + r) * CD + tid] = *(unsigned short*)&h;
  }
}

// ---------------- k2: emb -> Ehi bf16 [k][c] ----------------
__global__ __launch_bounds__(256) void splite_kernel(
    const float* __restrict__ emb, unsigned short* __restrict__ Ehi) {
  int n = blockIdx.x * 256 + threadIdx.x;
  __hip_bfloat16 h = __float2bfloat16(emb[n]);
  Ehi[n] = *(unsigned short*)&h;
}

// ---------------- k3: barrier-free LDS-free MFMA GEMM + per-256-code top-3 ----------------
// IDENTICAL to R7. The one experimental variable this round is WHERE Eg/Xg live
// (d_ws instead of d_out) — testing the "d_out reads are slow-path" theory.
__global__ __launch_bounds__(256, 2) void gemm_top3_kernel(
    const unsigned short* __restrict__ Eg,   // A [8192][256] bf16
    const unsigned short* __restrict__ Xg,   // B [8192][256] bf16
    u64* __restrict__ pK1, u64* __restrict__ pK2, u64* __restrict__ pK3) {
  __shared__ u64 redK[4][128][3];   // 12 KB

  int tid = threadIdx.x;
  int bid = blockIdx.x;             // 0..2047
  // XCD-chunked mapping: xcd = bid%8 owns cbx strip [xcd*4, xcd*4+4), rby 0..63,
  // traversed in 4x8 sub-chunks (working set ~1MB per L2).
  int xcd = bid & 7;
  int t   = bid >> 3;               // 0..255
  int rby_c = t >> 5;               // 0..7
  int r     = t & 31;
  int cbx = xcd * 4 + (r & 3);      // 0..31
  int rby = rby_c * 8 + (r >> 2);   // 0..63
  int wid = tid >> 6, lane = tid & 63;
  int llo = lane & 15, lhi = lane >> 4;
  int cb0w = cbx * 256 + wid * 64;  // this wave's 64 codes
  int rb0  = rby * 128;             // this wave's 128 zrows

  f32x4 acc[4][8];
#pragma unroll
  for (int i = 0; i < 4; ++i)
#pragma unroll
    for (int j = 0; j < 8; ++j) acc[i][j] = (f32x4){0.f, 0.f, 0.f, 0.f};

  // frag base addresses: row = base + 16*frag + llo, 16B k-slice at lhi*16
  const char* Ab = (const char*)Eg + ((size_t)(cb0w + llo)) * 512 + lhi * 16;
  const char* Bb = (const char*)Xg + ((size_t)(rb0  + llo)) * 512 + lhi * 16;

#define LA(dst, ks) { _Pragma("unroll") for (int i = 0; i < 4; ++i) \
    dst[i] = *(const short8*)(Ab + (size_t)i * 8192 + (ks) * 64); }
#define LB(dst, ks) { _Pragma("unroll") for (int j = 0; j < 8; ++j) \
    dst[j] = *(const short8*)(Bb + (size_t)j * 8192 + (ks) * 64); }
#define STEP(a, b) { _Pragma("unroll") for (int i = 0; i < 4; ++i) \
    _Pragma("unroll") for (int j = 0; j < 8; ++j) \
      acc[i][j] = __builtin_amdgcn_mfma_f32_16x16x32_bf16(a[i], b[j], acc[i][j], 0, 0, 0); }

  short8 a0[4], b0[8], a1[4], b1[8];
  LA(a0, 0) LB(b0, 0)
  LA(a1, 1) LB(b1, 1)
#pragma unroll
  for (int ks = 0; ks < 8; ks += 2) {
    STEP(a0, b0)
    if (ks + 2 < 8) { LA(a0, ks + 2) LB(b0, ks + 2) }
    STEP(a1, b1)
    if (ks + 3 < 8) { LA(a1, ks + 3) LB(b1, ks + 3) }
  }
#undef LA
#undef LB
#undef STEP

  // epilogue: v = -2*dot (x2 cancels per-row; monotone), top-3 per 64 codes,
  // reduce over lhi groups (xor 16,32 preserves llo). C/D layout m89-verified:
  // zrow = rb0 + 16j + llo, code = cb0w + 16i + 4*lhi + r4.  (R5/R7-validated)
#pragma unroll
  for (int j = 0; j < 8; ++j) {
    u64 t1 = ~0ull, t2 = ~0ull, t3 = ~0ull;
#pragma unroll
    for (int i = 0; i < 4; ++i)
#pragma unroll
      for (int r4 = 0; r4 < 4; ++r4) {
        float v = -2.0f * acc[i][j][r4];
        int code = cb0w + 16 * i + 4 * lhi + r4;
        ins3(makeKey(v, code), t1, t2, t3);
      }
#pragma unroll
    for (int off = 16; off < 64; off <<= 1) {
      u64 o1 = __shfl_xor(t1, off, 64);
      u64 o2 = __shfl_xor(t2, off, 64);
      u64 o3 = __shfl_xor(t3, off, 64);
      ins3(o1, t1, t2, t3); ins3(o2, t1, t2, t3); ins3(o3, t1, t2, t3);
    }
    if (lhi == 0) {
      int zl = 16 * j + llo;
      redK[wid][zl][0] = t1; redK[wid][zl][1] = t2; redK[wid][zl][2] = t3;
    }
  }
  __syncthreads();
  if (tid < 128) {
    u64 t1 = redK[0][tid][0], t2 = redK[0][tid][1], t3 = redK[0][tid][2];
#pragma unroll
    for (int w = 1; w < 4; ++w) {
      ins3(redK[w][tid][0], t1, t2, t3);
      ins3(redK[w][tid][1], t1, t2, t3);
      ins3(redK[w][tid][2], t1, t2, t3);
    }
    size_t o = (size_t)cbx * NROW + rb0 + tid;
    pK1[o] = t1; pK2[o] = t2; pK3[o] = t3;
  }
}

// ---------------- k4: merge blocks + exact re-rank (R2 semantics, R5-validated) ----------------
__global__ __launch_bounds__(256) void merge_rerank_kernel(
    const float* __restrict__ z, const float* __restrict__ emb,
    const u64* __restrict__ pK1, const u64* __restrict__ pK2,
    const u64* __restrict__ pK3, const float* __restrict__ x2g,
    int* __restrict__ idx, float* __restrict__ out) {
  int n = blockIdx.x * 256 + threadIdx.x;
  u64 kmin = ~0ull;
  for (int blk = 0; blk < NBLK; ++blk) {
    u64 k = pK1[(size_t)blk * NROW + n];
    if (k < kmin) kmin = k;
  }
  float vcut = keyVal(kmin) + MARGIN;
  int cand[8]; int nc = 0;
  for (int blk = 0; blk < NBLK; ++blk) {
    size_t o = (size_t)blk * NROW + n;
    u64 k1 = pK1[o], k2 = pK2[o], k3 = pK3[o];
    if (keyVal(k1) <= vcut && nc < 8) cand[nc++] = (int)(k1 & 0xffffffffu);
    if (keyVal(k2) <= vcut && nc < 8) cand[nc++] = (int)(k2 & 0xffffffffu);
    if (keyVal(k3) <= vcut && nc < 8) cand[nc++] = (int)(k3 & 0xffffffffu);
  }
  int b = n >> 10, hw = n & 1023;
  const float* zp = z + (size_t)b * (CD * HWSZ) + hw;
  float x2 = x2g[n];
  float bs = INFINITY; int bi = 0x7fffffff;
  for (int c0 = 0; c0 < nc; ++c0) {
    int k = cand[c0];
    const float* ep = emb + (size_t)k * CD;
    float acc = 0.f;
    for (int c = 0; c < CD; ++c)                 // sequential fmaf chain == R2 dot
      acc = fmaf(zp[(size_t)c * HWSZ], ep[c], acc);
    float s = fmaf(-2.f, acc, x2);               // single rounding == np grid
    if (s < bs || (s == bs && k < bi)) { bs = s; bi = k; }
  }
  idx[n] = bi;
  out[QOFF + 1 + n] = (float)bi;
}

// ---------------- k5: gather quantized + loss partials (R2-proven) ----------------
__global__ __launch_bounds__(256) void gather_kernel(
    const float* __restrict__ z, const float* __restrict__ emb,
    const int* __restrict__ idx, float* __restrict__ out,
    float* __restrict__ lossPart) {
  __shared__ int sidx[64];
  __shared__ float swsum[4];
  int tid = threadIdx.x;
  int bid = blockIdx.x;
  int n0 = bid * 64;
  if (tid < 64) sidx[tid] = idx[n0 + tid];
  __syncthreads();
  int lane = tid & 63;
  int cw = tid >> 6;
  int b = n0 >> 10;
  int hw = (n0 & 1023) + lane;
  const float* erow = emb + (size_t)sidx[lane] * CD;
  float lacc = 0.f;
  for (int ci = 0; ci < 64; ++ci) {
    int c = cw * 64 + ci;
    float q = erow[c];
    size_t o = (size_t)b * (CD * HWSZ) + (size_t)c * HWSZ + hw;
    float zv = z[o];
    out[o] = q;
    float d = q - zv;
    lacc += d * d;
  }
#pragma unroll
  for (int off = 32; off > 0; off >>= 1) lacc += __shfl_down(lacc, off, 64);
  if (lane == 0) swsum[cw] = lacc;
  __syncthreads();
  if (tid == 0) lossPart[bid] = swsum[0] + swsum[1] + swsum[2] + swsum[3];
}

__global__ void loss_kernel(const float* __restrict__ lossPart, float* __restrict__ out) {
  if (threadIdx.x == 0) {
    double s = 0.0;
    for (int i = 0; i < 128; ++i) s += (double)lossPart[i];
    out[QOFF] = (float)(s * 1.25 / (double)(NROW * CD));
  }
}

extern "C" void kernel_launch(void* const* d_in, const int* in_sizes, int n_in,
                              void* d_out, int out_size, void* d_ws, size_t ws_size,
                              hipStream_t stream) {
  const float* z   = (const float*)d_in[0];
  const float* emb = (const float*)d_in[1];
  float* out = (float*)d_out;

  // ws bump allocator
  char* wp = (char*)d_ws;
  u64* pK1 = (u64*)wp;                 wp += (size_t)NBLK * NROW * 8;   // 2 MB
  u64* pK2 = (u64*)wp;                 wp += (size_t)NBLK * NROW * 8;   // 2 MB
  u64* pK3 = (u64*)wp;                 wp += (size_t)NBLK * NROW * 8;   // 2 MB
  float* x2g = (float*)wp;             wp += (size_t)NROW * 4;
  int* idx = (int*)wp;                 wp += (size_t)NROW * 4;
  float* lossPart = (float*)wp;        wp += 128 * 4;

  // THE R8 EXPERIMENT: bf16 operands in d_ws (normal device memory) instead of
  // d_out (suspected fine-grained/slow-read). Fallback to d_out if ws too small.
  size_t opBytes = (size_t)KCODE * CD * 2;   // 4 MB each
  unsigned short* Ehi;
  unsigned short* Xhi;
  size_t used = (size_t)(wp - (char*)d_ws);
  if (ws_size >= used + 2 * opBytes) {
    Ehi = (unsigned short*)wp;
    Xhi = (unsigned short*)(wp + opBytes);
  } else {
    Ehi = (unsigned short*)d_out;
    Xhi = (unsigned short*)d_out + (size_t)KCODE * CD;
  }

  hipLaunchKernelGGL(splitz_x2_kernel, dim3(NROW / 32), dim3(256), 0, stream, z, Xhi, x2g);
  hipLaunchKernelGGL(splite_kernel, dim3((KCODE * CD) / 256), dim3(256), 0, stream, emb, Ehi);
  hipLaunchKernelGGL(gemm_top3_kernel, dim3((KCODE / 256) * (NROW / 128)), dim3(256), 0, stream,
                     Ehi, Xhi, pK1, pK2, pK3);
  hipLaunchKernelGGL(merge_rerank_kernel, dim3(NROW / 256), dim3(256), 0, stream,
                     z, emb, pK1, pK2, pK3, x2g, idx, out);
  hipLaunchKernelGGL(gather_kernel, dim3(NROW / 64), dim3(256), 0, stream,
                     z, emb, idx, out, lossPart);
  hipLaunchKernelGGL(loss_kernel, dim3(1), dim3(64), 0, stream, lossPart, out);
}